// Round 1
// baseline (141.747 us; speedup 1.0000x reference)
//
#include <hip/hip_runtime.h>

// Problem: focal Tversky loss over (8,10,512,512) fp32 logits, (8,512,512) int32 targets.
// Key simplification: argmax(softmax(x)) == argmax(x) -> no softmax/exp needed.
// Memory-bound: must read channels 1..9 (75.5 MB) + targets (8.4 MB) ~= 84 MB once.

#define HW        262144   // 512*512
#define HW4       65536    // HW/4 (float4 groups per image plane)
#define NGROUPS   524288   // 8*HW/4  (4-pixel groups total)

// cnt layout: [0..8] = TP per class, [9..17] = target count, [18..26] = pred count
__global__ __launch_bounds__(256) void ftl_hist(const float* __restrict__ inp,
                                                const int* __restrict__ tgt,
                                                unsigned int* __restrict__ cnt) {
    __shared__ unsigned int s[27];
    const int tid = threadIdx.x;
    if (tid < 27) s[tid] = 0u;
    __syncthreads();

    const float4* f4  = reinterpret_cast<const float4*>(inp);
    const int4*   t4p = reinterpret_cast<const int4*>(tgt);

    int i = blockIdx.x * blockDim.x + tid;
    const int gstride = gridDim.x * blockDim.x;

    for (; i < NGROUPS; i += gstride) {
        const int b  = i >> 16;        // image index (HW4 = 2^16 groups/image)
        const int gi = i & (HW4 - 1);  // float4-group index within image
        // channel 1 base for this group; channel stride = HW4 float4s
        const float4* base = f4 + (((size_t)(b * 10 + 1)) << 16) + gi;

        float4 v = base[0];
        float bv0 = v.x, bv1 = v.y, bv2 = v.z, bv3 = v.w;
        int   bc0 = 1,   bc1 = 1,   bc2 = 1,   bc3 = 1;
#pragma unroll
        for (int c = 2; c <= 9; ++c) {
            float4 w = base[((size_t)(c - 1)) << 16];
            if (w.x > bv0) { bv0 = w.x; bc0 = c; }
            if (w.y > bv1) { bv1 = w.y; bc1 = c; }
            if (w.z > bv2) { bv2 = w.z; bc2 = c; }
            if (w.w > bv3) { bv3 = w.w; bc3 = c; }
        }

        const int4 t = t4p[i];
        if (t.x) { atomicAdd(&s[9 + t.x - 1], 1u); atomicAdd(&s[18 + bc0 - 1], 1u); if (bc0 == t.x) atomicAdd(&s[t.x - 1], 1u); }
        if (t.y) { atomicAdd(&s[9 + t.y - 1], 1u); atomicAdd(&s[18 + bc1 - 1], 1u); if (bc1 == t.y) atomicAdd(&s[t.y - 1], 1u); }
        if (t.z) { atomicAdd(&s[9 + t.z - 1], 1u); atomicAdd(&s[18 + bc2 - 1], 1u); if (bc2 == t.z) atomicAdd(&s[t.z - 1], 1u); }
        if (t.w) { atomicAdd(&s[9 + t.w - 1], 1u); atomicAdd(&s[18 + bc3 - 1], 1u); if (bc3 == t.w) atomicAdd(&s[t.w - 1], 1u); }
    }

    __syncthreads();
    if (tid < 27) atomicAdd(&cnt[tid], s[tid]);
}

__global__ void ftl_final(const unsigned int* __restrict__ cnt, float* __restrict__ out) {
    if (threadIdx.x == 0 && blockIdx.x == 0) {
        double loss = 0.0;
#pragma unroll
        for (int c = 0; c < 9; ++c) {
            const double TP = (double)cnt[c];
            const double FN = (double)cnt[9 + c]  - TP;
            const double FP = (double)cnt[18 + c] - TP;
            const double tv = (TP + 1.0) / (TP + 0.7 * FN + 0.3 * FP + 1.0);
            loss += pow(1.0 - tv, 4.0 / 3.0);
        }
        out[0] = (float)loss;
    }
}

extern "C" void kernel_launch(void* const* d_in, const int* in_sizes, int n_in,
                              void* d_out, int out_size, void* d_ws, size_t ws_size,
                              hipStream_t stream) {
    const float* inp = (const float*)d_in[0];
    const int*   tgt = (const int*)d_in[1];
    unsigned int* cnt = (unsigned int*)d_ws;   // 27 counters
    float* out = (float*)d_out;

    // ws is re-poisoned to 0xAA before every timed launch -> zero it ourselves.
    hipMemsetAsync(cnt, 0, 27 * sizeof(unsigned int), stream);

    // 2048 blocks * 256 threads = NGROUPS threads: one 4-pixel group each.
    ftl_hist<<<dim3(NGROUPS / 256), dim3(256), 0, stream>>>(inp, tgt, cnt);
    ftl_final<<<dim3(1), dim3(64), 0, stream>>>(cnt, out);
}

// Round 2
// 131.160 us; speedup vs baseline: 1.0807x; 1.0807x over previous
//
#include <hip/hip_runtime.h>

// Focal Tversky loss over (8,10,512,512) fp32 logits, (8,512,512) int32 targets.
// argmax(softmax(x)) == argmax(x) -> no softmax needed. Memory-bound:
// channels 1..9 (75.5 MB) + targets (8.4 MB) ~= 84 MB read once -> ~13.3 us floor.
//
// Two launches, no memset: each hist block stores 27 partial counts to its own
// ws slot (plain stores -> no zero-init needed despite 0xAA ws poison); the
// reduce kernel sums partials (transposed layout, coalesced) + Tversky epilogue.

#define HW4     65536    // 512*512/4 (float4 groups per plane), = 2^16
#define NGROUPS 524288   // 8 * HW4
#define NBLK    2048     // hist grid; NBLK*256 == NGROUPS (one group per thread)

// partial layout (transposed for coalesced reduce): pw[c*NBLK + block]
// c in [0,27): 0..8 TP, 9..17 target count, 18..26 pred count
__global__ __launch_bounds__(256) void ftl_hist(const float* __restrict__ inp,
                                                const int* __restrict__ tgt,
                                                unsigned int* __restrict__ pw) {
    __shared__ unsigned int s[27];
    const int tid = threadIdx.x;
    if (tid < 27) s[tid] = 0u;
    __syncthreads();

    const int i  = blockIdx.x * 256 + tid;     // 4-pixel group index
    const int b  = i >> 16;                    // image index
    const int gi = i & (HW4 - 1);              // group within image

    const float4* base = reinterpret_cast<const float4*>(inp)
                       + (((size_t)(b * 10 + 1)) << 16) + gi;  // channel 1

    float4 v = base[0];
    float bv0 = v.x, bv1 = v.y, bv2 = v.z, bv3 = v.w;
    int   bc0 = 1,   bc1 = 1,   bc2 = 1,   bc3 = 1;
#pragma unroll
    for (int c = 2; c <= 9; ++c) {
        float4 w = base[((size_t)(c - 1)) << 16];
        if (w.x > bv0) { bv0 = w.x; bc0 = c; }
        if (w.y > bv1) { bv1 = w.y; bc1 = c; }
        if (w.z > bv2) { bv2 = w.z; bc2 = c; }
        if (w.w > bv3) { bv3 = w.w; bc3 = c; }
    }

    const int4 t = reinterpret_cast<const int4*>(tgt)[i];
    if (t.x) { atomicAdd(&s[9 + t.x - 1], 1u); atomicAdd(&s[18 + bc0 - 1], 1u); if (bc0 == t.x) atomicAdd(&s[t.x - 1], 1u); }
    if (t.y) { atomicAdd(&s[9 + t.y - 1], 1u); atomicAdd(&s[18 + bc1 - 1], 1u); if (bc1 == t.y) atomicAdd(&s[t.y - 1], 1u); }
    if (t.z) { atomicAdd(&s[9 + t.z - 1], 1u); atomicAdd(&s[18 + bc2 - 1], 1u); if (bc2 == t.z) atomicAdd(&s[t.z - 1], 1u); }
    if (t.w) { atomicAdd(&s[9 + t.w - 1], 1u); atomicAdd(&s[18 + bc3 - 1], 1u); if (bc3 == t.w) atomicAdd(&s[t.w - 1], 1u); }

    __syncthreads();
    if (tid < 27) pw[tid * NBLK + blockIdx.x] = s[tid];
}

// One block, 896 threads: 27 groups of 32 lanes each sum one counter row
// (coalesced), shuffle-reduce, thread 0 does the 9-term Tversky sum in double.
__global__ __launch_bounds__(896) void ftl_reduce(const unsigned int* __restrict__ pw,
                                                  float* __restrict__ out) {
    __shared__ double cs[27];
    const int tid = threadIdx.x;
    const int g = tid >> 5;
    const int l = tid & 31;
    if (g < 27) {
        unsigned int sum = 0;
        const unsigned int* row = pw + g * NBLK;
#pragma unroll 8
        for (int k = l; k < NBLK; k += 32) sum += row[k];
#pragma unroll
        for (int off = 16; off; off >>= 1) sum += __shfl_down(sum, off, 32);
        if (l == 0) cs[g] = (double)sum;
    }
    __syncthreads();
    if (tid == 0) {
        double loss = 0.0;
#pragma unroll
        for (int c = 0; c < 9; ++c) {
            const double TP = cs[c];
            const double FN = cs[9 + c]  - TP;
            const double FP = cs[18 + c] - TP;
            const double tv = (TP + 1.0) / (TP + 0.7 * FN + 0.3 * FP + 1.0);
            loss += pow(1.0 - tv, 4.0 / 3.0);
        }
        out[0] = (float)loss;
    }
}

extern "C" void kernel_launch(void* const* d_in, const int* in_sizes, int n_in,
                              void* d_out, int out_size, void* d_ws, size_t ws_size,
                              hipStream_t stream) {
    const float* inp = (const float*)d_in[0];
    const int*   tgt = (const int*)d_in[1];
    unsigned int* pw = (unsigned int*)d_ws;    // 27*2048 partial counters, no init needed
    float* out = (float*)d_out;

    ftl_hist<<<dim3(NBLK), dim3(256), 0, stream>>>(inp, tgt, pw);
    ftl_reduce<<<dim3(1), dim3(896), 0, stream>>>(pw, out);
}

// Round 3
// 130.759 us; speedup vs baseline: 1.0840x; 1.0031x over previous
//
#include <hip/hip_runtime.h>

// Focal Tversky loss over (8,10,512,512) fp32 logits, (8,512,512) int32 targets.
// argmax(softmax(x)) == argmax(x) -> no softmax needed. Memory-bound:
// channels 1..9 (75.5 MB) + targets (8.4 MB) ~= 84 MB read once -> ~13.3 us floor.
//
// R2: replaced per-pixel conditional LDS atomics (up to 12 ds_atomic_add/wave,
// ~7-way same-address serialization on the LDS pipe) with ballot-based wave
// histogramming: wave-wide v_cmp ballots + scalar popcounts, counts live in
// wave-uniform registers. No atomics anywhere in the hot path.

#define HW4     65536    // 512*512/4 (float4 groups per plane), = 2^16
#define NGROUPS 524288   // 8 * HW4
#define NBLK    2048     // hist grid; NBLK*256 == NGROUPS (one group per thread)

// partial layout (transposed for coalesced reduce): pw[c*NBLK + block]
// c in [0,27): 0..8 TP, 9..17 target count, 18..26 pred count
__global__ __launch_bounds__(256) void ftl_hist(const float* __restrict__ inp,
                                                const int* __restrict__ tgt,
                                                unsigned int* __restrict__ pw) {
    __shared__ unsigned int s[4][27];
    const int tid  = threadIdx.x;
    const int wave = tid >> 6;
    const int lane = tid & 63;

    const int i  = blockIdx.x * 256 + tid;     // 4-pixel group index
    const int b  = i >> 16;                    // image index
    const int gi = i & (HW4 - 1);              // group within image

    const float4* base = reinterpret_cast<const float4*>(inp)
                       + (((size_t)(b * 10 + 1)) << 16) + gi;  // channel 1

    float4 v = base[0];
    float bv0 = v.x, bv1 = v.y, bv2 = v.z, bv3 = v.w;
    int   bc0 = 1,   bc1 = 1,   bc2 = 1,   bc3 = 1;
#pragma unroll
    for (int c = 2; c <= 9; ++c) {
        float4 w = base[((size_t)(c - 1)) << 16];
        if (w.x > bv0) { bv0 = w.x; bc0 = c; }
        if (w.y > bv1) { bv1 = w.y; bc1 = c; }
        if (w.z > bv2) { bv2 = w.z; bc2 = c; }
        if (w.w > bv3) { bv3 = w.w; bc3 = c; }
    }

    const int4 t = reinterpret_cast<const int4*>(tgt)[i];

    unsigned int cTP[9], cT[9], cP[9];
#pragma unroll
    for (int j = 0; j < 9; ++j) { cTP[j] = 0u; cT[j] = 0u; cP[j] = 0u; }

    // per-component valid masks (t != 0), wave-uniform u64s
    const unsigned long long vx = __ballot(t.x != 0);
    const unsigned long long vy = __ballot(t.y != 0);
    const unsigned long long vz = __ballot(t.z != 0);
    const unsigned long long vw = __ballot(t.w != 0);

#pragma unroll
    for (int c = 1; c <= 9; ++c) {
        const int j = c - 1;
        {   // component x
            const unsigned long long tm = __ballot(t.x == c);
            const unsigned long long pm = __ballot(bc0 == c);
            cT[j]  += (unsigned int)__builtin_popcountll(tm);
            cP[j]  += (unsigned int)__builtin_popcountll(pm & vx);
            cTP[j] += (unsigned int)__builtin_popcountll(tm & pm);
        }
        {   // component y
            const unsigned long long tm = __ballot(t.y == c);
            const unsigned long long pm = __ballot(bc1 == c);
            cT[j]  += (unsigned int)__builtin_popcountll(tm);
            cP[j]  += (unsigned int)__builtin_popcountll(pm & vy);
            cTP[j] += (unsigned int)__builtin_popcountll(tm & pm);
        }
        {   // component z
            const unsigned long long tm = __ballot(t.z == c);
            const unsigned long long pm = __ballot(bc2 == c);
            cT[j]  += (unsigned int)__builtin_popcountll(tm);
            cP[j]  += (unsigned int)__builtin_popcountll(pm & vz);
            cTP[j] += (unsigned int)__builtin_popcountll(tm & pm);
        }
        {   // component w
            const unsigned long long tm = __ballot(t.w == c);
            const unsigned long long pm = __ballot(bc3 == c);
            cT[j]  += (unsigned int)__builtin_popcountll(tm);
            cP[j]  += (unsigned int)__builtin_popcountll(pm & vw);
            cTP[j] += (unsigned int)__builtin_popcountll(tm & pm);
        }
    }

    // combine 4 waves via plain LDS stores (counts are wave-uniform)
    if (lane == 0) {
#pragma unroll
        for (int j = 0; j < 9; ++j) {
            s[wave][j]      = cTP[j];
            s[wave][9 + j]  = cT[j];
            s[wave][18 + j] = cP[j];
        }
    }
    __syncthreads();
    if (tid < 27)
        pw[tid * NBLK + blockIdx.x] = s[0][tid] + s[1][tid] + s[2][tid] + s[3][tid];
}

// One block, 896 threads: 27 groups of 32 lanes each sum one counter row
// (coalesced), shuffle-reduce, thread 0 does the 9-term Tversky sum in double.
__global__ __launch_bounds__(896) void ftl_reduce(const unsigned int* __restrict__ pw,
                                                  float* __restrict__ out) {
    __shared__ double cs[27];
    const int tid = threadIdx.x;
    const int g = tid >> 5;
    const int l = tid & 31;
    if (g < 27) {
        unsigned int sum = 0;
        const unsigned int* row = pw + g * NBLK;
#pragma unroll 8
        for (int k = l; k < NBLK; k += 32) sum += row[k];
#pragma unroll
        for (int off = 16; off; off >>= 1) sum += __shfl_down(sum, off, 32);
        if (l == 0) cs[g] = (double)sum;
    }
    __syncthreads();
    if (tid == 0) {
        double loss = 0.0;
#pragma unroll
        for (int c = 0; c < 9; ++c) {
            const double TP = cs[c];
            const double FN = cs[9 + c]  - TP;
            const double FP = cs[18 + c] - TP;
            const double tv = (TP + 1.0) / (TP + 0.7 * FN + 0.3 * FP + 1.0);
            loss += pow(1.0 - tv, 4.0 / 3.0);
        }
        out[0] = (float)loss;
    }
}

extern "C" void kernel_launch(void* const* d_in, const int* in_sizes, int n_in,
                              void* d_out, int out_size, void* d_ws, size_t ws_size,
                              hipStream_t stream) {
    const float* inp = (const float*)d_in[0];
    const int*   tgt = (const int*)d_in[1];
    unsigned int* pw = (unsigned int*)d_ws;    // 27*2048 partial counters, no init needed
    float* out = (float*)d_out;

    ftl_hist<<<dim3(NBLK), dim3(256), 0, stream>>>(inp, tgt, pw);
    ftl_reduce<<<dim3(1), dim3(896), 0, stream>>>(pw, out);
}